// Round 8
// baseline (330.565 us; speedup 1.0000x reference)
//
#include <hip/hip_runtime.h>

#define LEVELS 16
#define TSIZE 524288
#define TMASK (TSIZE - 1)
#define TPB 256
#define GPPT 8                  // gather: points per thread
#define CHUNK (TPB * GPPT)      // 2048 points per chunk/slab

#define C0 4096                 // 16^3 level-0 cells
#define C1 13824                // 24^3 level-1 cells
#define C1H 6912                // half of C1 (two-pass LDS staging)
#define GLO 4                   // gather_lo: chunks per block

typedef float f2v __attribute__((ext_vector_type(2)));
typedef float f4v __attribute__((ext_vector_type(4)));

// int(16 * 1.5**l), exact as float32
__device__ __constant__ float c_res[LEVELS] = {
    16.f, 24.f, 36.f, 54.f, 81.f, 121.f, 182.f, 273.f,
    410.f, 615.f, 922.f, 1383.f, 2075.f, 3113.f, 4670.f, 7006.f
};

__device__ __forceinline__ unsigned hash_iii(int ix, int iy, int iz)
{
    return ((unsigned)ix * 73856093u
          ^ (unsigned)iy * 19349663u
          ^ (unsigned)iz * 83492791u) & TMASK;
}

__device__ __forceinline__ unsigned hash_idx(float px, float py, float pz, float r)
{
    return hash_iii((int)floorf(px * r), (int)floorf(py * r), (int)floorf(pz * r));
}

// Evidence ledger (rounds 1-7):
//  R1 8-deep gather batching: null -> not per-wave-MLP-limited.
//  R2 spin-flag fusion: 3x regression -> never trade resident miss
//     parallelism for sync.
//  R3 NT x loads: FETCH -150MB but +20us -> feeder LATENCY is on the
//     critical resource (slot-cycles = misses x latency).
//  R4 16B/lane @ 64B-stride NT stores: WRITE 262->633MB RMW blowup ->
//     NT store insts must cover full contiguous lines per wave.
//  R5 LDS-staged x (VMEM insts 40->22, occ 82->61%): null -> not
//     request-slot- or occupancy-limited. Limiter = chip-wide MSHR
//     slot-cycles (misses x latency / ~16K outstanding lines).
//  R6 idx-precompute, NT idx stores: idx landed in HBM (900cy) -> slower.
//  R7 idx-precompute, CACHED idx stores: L3-resident feeder -> gather
//     278->210us, total 321. Model quantitative: (33.5M*200 + 2.1M*550)
//     /16384 slots = 203us.
//  R8 (this): levels 0-1 touch only 4096/13824 distinct cells -> serve
//     them from LDS-dense remapped tables (ds_read costs no MSHR slot).
//     Main gather drops to 14 levels on a BALANCED sequential-pinned
//     XCD work list (each XCD: contiguous 1.75-level span, one table at
//     a time in its L2 - same invariant as the proven 2-half scheme).

// idx layout: chunk-tiled: idxw[(c*LEVELS + l)*CHUNK + local]
// ws layout: [slabs][idx][dense0 32KB][dense1 108KB]

// ---------------- Kernel R: dense remap for levels 0-1 -----------------------
// dense[cell] = table[hash(cell)] (bit-exact copy; linear = ix + r*(iy+r*iz))
__global__ __launch_bounds__(TPB) void remap_kernel(
    const float* __restrict__ tables,
    f2v* __restrict__ dense)
{
    const int e = blockIdx.x * TPB + threadIdx.x;
    if (e >= C0 + C1) return;
    int id, r, lvl;
    if (e < C0) { lvl = 0; r = 16; id = e; }
    else        { lvl = 1; r = 24; id = e - C0; }
    int ix, iy, iz;
    if (r == 16) { ix = id & 15; iy = (id >> 4) & 15; iz = id >> 8; }
    else         { ix = id % 24; iy = (id / 24) % 24; iz = id / 576; }
    const unsigned h = hash_iii(ix, iy, iz);
    const float* __restrict__ tbl = tables + (size_t)lvl * (TSIZE * 2);
    dense[e] = *reinterpret_cast<const f2v*>(tbl + 2 * (size_t)h);
}

// ---------------- Kernel 0: per-chunk hash precompute ------------------------
// lo_dense: levels 0-1 get LINEAR cell ids (feed gather_lo's dense LDS);
// otherwise hashed ids for all levels (R7 fallback path).
__global__ __launch_bounds__(TPB) void hash_kernel(
    const float* __restrict__ x,
    unsigned* __restrict__ idxw,
    int n, int lo_dense)
{
    __shared__ float xs[CHUNK * 3];         // 24KB: this chunk's x
    const int c = blockIdx.x;
    const int t = threadIdx.x;
    const long long base = (long long)c * CHUNK;
    unsigned* __restrict__ islab = idxw + (size_t)c * LEVELS * CHUNK;

    if (base + CHUNK <= n) {
        const f4v* __restrict__ xg = reinterpret_cast<const f4v*>(x + 3 * base);
#pragma unroll
        for (int j = 0; j < 6; ++j) {
            const int s = j * TPB + t;
            *reinterpret_cast<f4v*>(&xs[4 * s]) = xg[s];
        }
        __syncthreads();

#pragma unroll
        for (int j = 0; j < GPPT; ++j) {
            const int local = j * TPB + t;
            const float px = xs[3 * local + 0];
            const float py = xs[3 * local + 1];
            const float pz = xs[3 * local + 2];
#pragma unroll
            for (int l = 0; l < LEVELS; ++l) {
                const float rs = c_res[l];
                const int ix = (int)floorf(px * rs);
                const int iy = (int)floorf(py * rs);
                const int iz = (int)floorf(pz * rs);
                unsigned id;
                if (lo_dense && l < 2) {
                    const int ri = (l == 0) ? 16 : 24;
                    id = (unsigned)(ix + ri * (iy + ri * iz));
                } else {
                    id = hash_iii(ix, iy, iz);
                }
                islab[l * CHUNK + local] = id;   // cached (R7: L3-resident)
            }
        }
    } else {
        for (int j = 0; j < GPPT; ++j) {
            const int local = j * TPB + t;
            const long long p = base + local;
            if (p < n) {
                const float px = x[3 * p + 0];
                const float py = x[3 * p + 1];
                const float pz = x[3 * p + 2];
                for (int l = 0; l < LEVELS; ++l) {
                    const float rs = c_res[l];
                    const int ix = (int)floorf(px * rs);
                    const int iy = (int)floorf(py * rs);
                    const int iz = (int)floorf(pz * rs);
                    unsigned id;
                    if (lo_dense && l < 2) {
                        const int ri = (l == 0) ? 16 : 24;
                        id = (unsigned)(ix + ri * (iy + ri * iz));
                    } else {
                        id = hash_iii(ix, iy, iz);
                    }
                    islab[l * CHUNK + local] = id;
                }
            }
        }
    }
}

// ---------------- Kernel L: levels 0-1 via LDS-dense tables ------------------
// blocks [0,nb): level 0 (stage 32KB dense0, single pass)
// blocks [nb,2nb): level 1 (stage dense1 in two 54KB passes; results held in
// registers across passes; full-line NT stores at the end - R4 rule)
// LDS gathers cost no MSHR slots -> removes these levels from the gather
// bottleneck entirely.
__global__ __launch_bounds__(TPB) void gather_lo(
    const unsigned* __restrict__ idxr,
    const f2v* __restrict__ dense,
    f2v* __restrict__ ws,
    int n, int bpl, int nb)
{
    __shared__ f2v dlds[C1H];               // 54KB
    const int b = blockIdx.x;
    const int t = threadIdx.x;
    const int lvl = (b < nb) ? 0 : 1;
    const int cbase = (lvl ? (b - nb) : b) * GLO;

    if (lvl == 0) {
        // stage dense0 (4096 f2v) as 2048 f4v
        const f4v* __restrict__ d0 = reinterpret_cast<const f4v*>(dense);
        f4v* __restrict__ dst = reinterpret_cast<f4v*>(dlds);
#pragma unroll
        for (int s = 0; s < C0 / 2 / TPB; ++s)
            dst[s * TPB + t] = d0[s * TPB + t];
        __syncthreads();

        for (int cc = 0; cc < GLO; ++cc) {
            const int c = cbase + cc;
            if (c >= bpl) break;
            const long long base = (long long)c * CHUNK;
            const unsigned* __restrict__ islab = idxr + ((size_t)c * LEVELS + 0) * CHUNK;
            f2v* __restrict__ slab = ws + ((size_t)c * LEVELS + 0) * CHUNK;
            if (base + CHUNK <= n) {
                unsigned idx[GPPT];
#pragma unroll
                for (int j = 0; j < GPPT; ++j)
                    idx[j] = islab[j * TPB + t];
                f2v e[GPPT];
#pragma unroll
                for (int j = 0; j < GPPT; ++j)
                    e[j] = dlds[idx[j]];
#pragma unroll
                for (int j = 0; j < GPPT; ++j)
                    __builtin_nontemporal_store(e[j], slab + j * TPB + t);
            } else {
                for (int j = 0; j < GPPT; ++j) {
                    const int local = j * TPB + t;
                    if (base + local < n)
                        slab[local] = dlds[islab[local]];   // tail: cached
                }
            }
        }
    } else {
        // ---- level 1: gather idx for all GLO chunks into registers ----
        unsigned I[GLO][GPPT];
        for (int cc = 0; cc < GLO; ++cc) {
            const int c = cbase + cc;
            const unsigned* __restrict__ islab =
                idxr + ((size_t)c * LEVELS + 1) * CHUNK;
            for (int j = 0; j < GPPT; ++j) {
                const int local = j * TPB + t;
                const long long p = (long long)c * CHUNK + local;
                I[cc][j] = (c < bpl && p < n) ? islab[local] : 0xFFFFFFFFu;
            }
        }
        f2v E[GLO][GPPT];

        // pass A: cells [0, C1H)
        for (int s = t; s < C1H; s += TPB) dlds[s] = dense[C0 + s];
        __syncthreads();
        for (int cc = 0; cc < GLO; ++cc)
            for (int j = 0; j < GPPT; ++j)
                if (I[cc][j] < C1H) E[cc][j] = dlds[I[cc][j]];
        __syncthreads();

        // pass B: cells [C1H, C1)
        for (int s = t; s < C1H; s += TPB) dlds[s] = dense[C0 + C1H + s];
        __syncthreads();
        for (int cc = 0; cc < GLO; ++cc)
            for (int j = 0; j < GPPT; ++j)
                if (I[cc][j] >= C1H && I[cc][j] < C1)
                    E[cc][j] = dlds[I[cc][j] - C1H];

        // stores: full-line NT for complete chunks (R4 rule)
        for (int cc = 0; cc < GLO; ++cc) {
            const int c = cbase + cc;
            if (c >= bpl) break;
            const long long base = (long long)c * CHUNK;
            f2v* __restrict__ slab = ws + ((size_t)c * LEVELS + 1) * CHUNK;
            if (base + CHUNK <= n) {
#pragma unroll
                for (int j = 0; j < GPPT; ++j)
                    __builtin_nontemporal_store(E[cc][j], slab + j * TPB + t);
            } else {
                for (int j = 0; j < GPPT; ++j) {
                    const int local = j * TPB + t;
                    if (base + local < n) slab[local] = E[cc][j];
                }
            }
        }
    }
}

// ---------------- Kernel A: XCD-balanced level-major gather (idx-fed) --------
// Work list w in [0, nlv*bpl), level-major. XCD k owns the contiguous range
// [floor(total*k/8), floor(total*(k+1)/8)) -> equal work per XCD; within an
// XCD the sequence is level-major, so its 4MB L2 holds ONE table at a time
// (the proven pinning invariant, generalized from the 2-half scheme).
// Block b: k = b&7 (round-robin dispatch -> XCD k), s = b>>3.
__global__ __launch_bounds__(TPB) void gather_kernel(
    const unsigned* __restrict__ idxr,
    const float* __restrict__ tables,
    f2v* __restrict__ ws,
    int n, int bpl, int lvl_start, int nlv)
{
    const long long total = (long long)nlv * bpl;
    const int k = blockIdx.x & 7;
    const long long s = blockIdx.x >> 3;
    const long long w = ((total * k) >> 3) + s;
    if (w >= ((total * (k + 1)) >> 3)) return;
    const int lrel = (int)(w / bpl);
    const int level = lvl_start + lrel;
    const int c = (int)(w - (long long)lrel * bpl);
    const int t = threadIdx.x;

    const float* __restrict__ tbl = tables + (size_t)level * (TSIZE * 2);
    f2v* __restrict__ slab = ws + ((size_t)c * LEVELS + level) * CHUNK;
    const unsigned* __restrict__ islab = idxr + ((size_t)c * LEVELS + level) * CHUNK;
    const long long base = (long long)c * CHUNK;

    if (base + CHUNK <= n) {
        unsigned idx[GPPT];
#pragma unroll
        for (int j = 0; j < GPPT; ++j)
            idx[j] = islab[j * TPB + t];

        // 8 independent random 8B gathers in flight (XCD-local L2)
        f2v e[GPPT];
#pragma unroll
        for (int j = 0; j < GPPT; ++j)
            e[j] = *reinterpret_cast<const f2v*>(tbl + 2 * (size_t)idx[j]);

#pragma unroll
        for (int j = 0; j < GPPT; ++j)
            __builtin_nontemporal_store(e[j], slab + j * TPB + t);
    } else {
        for (int j = 0; j < GPPT; ++j) {
            const int local = j * TPB + t;
            if (base + local < n) {
                const unsigned id = islab[local];
                const f2v e = *reinterpret_cast<const f2v*>(tbl + 2 * (size_t)id);
                __builtin_nontemporal_store(e, slab + local);
            }
        }
    }
}

// ------------- Kernel A': x-fed gather (fallback when idx doesn't fit) -------
__global__ __launch_bounds__(TPB) void gather_x_kernel(
    const float* __restrict__ x,
    const float* __restrict__ tables,
    f2v* __restrict__ ws,
    int n, int bpl)
{
    const int b = blockIdx.x;
    const int half = b / (8 * bpl);
    const int r = b % (8 * bpl);
    const int level = half * 8 + (r & 7);
    const int c = r >> 3;
    const int t = threadIdx.x;

    const float rs = c_res[level];
    const float* __restrict__ tbl = tables + (size_t)level * (TSIZE * 2);
    f2v* __restrict__ slab = ws + ((size_t)c * LEVELS + level) * CHUNK;
    const long long base = (long long)c * CHUNK;

    if (base + CHUNK <= n) {
        const float* __restrict__ xb = x + 3 * base;
        float px[GPPT], py[GPPT], pz[GPPT];
#pragma unroll
        for (int j = 0; j < GPPT; ++j) {
            const int local = j * TPB + t;
            px[j] = xb[3 * local + 0];
            py[j] = xb[3 * local + 1];
            pz[j] = xb[3 * local + 2];
        }
        unsigned idx[GPPT];
#pragma unroll
        for (int j = 0; j < GPPT; ++j)
            idx[j] = hash_idx(px[j], py[j], pz[j], rs);
        f2v e[GPPT];
#pragma unroll
        for (int j = 0; j < GPPT; ++j)
            e[j] = *reinterpret_cast<const f2v*>(tbl + 2 * (size_t)idx[j]);
#pragma unroll
        for (int j = 0; j < GPPT; ++j)
            __builtin_nontemporal_store(e[j], slab + j * TPB + t);
    } else {
#pragma unroll
        for (int j = 0; j < GPPT; ++j) {
            const int local = j * TPB + t;
            const long long p = base + local;
            if (p < n) {
                const float qx = x[3 * p + 0];
                const float qy = x[3 * p + 1];
                const float qz = x[3 * p + 2];
                const unsigned idx = hash_idx(qx, qy, qz, rs);
                const f2v e = *reinterpret_cast<const f2v*>(tbl + 2 * (size_t)idx);
                __builtin_nontemporal_store(e, slab + local);
            }
        }
    }
}

// ---------------- Kernel B: assemble (slab ws -> point-major out rows) -------
// At HBM roofline for its 524MB (~6TB/s measured). Unchanged.
__global__ __launch_bounds__(TPB) void assemble_kernel(
    const f2v* __restrict__ ws,
    float* __restrict__ out,
    int n)
{
    const int c = blockIdx.x;
    const int t = threadIdx.x;
    const int q = t & 7;
    const int sub = t >> 3;  // 0..31

    const f2v* __restrict__ wa = ws + ((size_t)c * LEVELS + 2 * q) * CHUNK;
    const f2v* __restrict__ wb = wa + CHUNK;
    const long long base = (long long)c * CHUNK;

    if (base + CHUNK <= n) {
#pragma unroll 8
        for (int u = 0; u < CHUNK / 64; ++u) {
            const int lp = 2 * (u * 32 + sub);
            const f4v a = __builtin_nontemporal_load(
                reinterpret_cast<const f4v*>(wa + lp));
            const f4v b = __builtin_nontemporal_load(
                reinterpret_cast<const f4v*>(wb + lp));
            f4v v0, v1;
            v0.x = a.x; v0.y = a.y; v0.z = b.x; v0.w = b.y;
            v1.x = a.z; v1.y = a.w; v1.z = b.z; v1.w = b.w;
            float* row = out + (size_t)(base + lp) * (2 * LEVELS) + 4 * q;
            __builtin_nontemporal_store(v0, reinterpret_cast<f4v*>(row));
            __builtin_nontemporal_store(v1, reinterpret_cast<f4v*>(row + 2 * LEVELS));
        }
    } else {
#pragma unroll 8
        for (int u = 0; u < CHUNK / 32; ++u) {
            const int lp = u * 32 + sub;
            const long long pt = base + lp;
            if (pt < n) {
                const f2v a = __builtin_nontemporal_load(wa + lp);
                const f2v b = __builtin_nontemporal_load(wb + lp);
                f4v v;
                v.x = a.x; v.y = a.y; v.z = b.x; v.w = b.y;
                __builtin_nontemporal_store(
                    v, reinterpret_cast<f4v*>(out + (size_t)pt * (2 * LEVELS) + 4 * q));
            }
        }
    }
}

// ---------------- Fallback (ws too small): round-3 fused kernel --------------
#define ROWW 34
__global__ __launch_bounds__(TPB) void hashgrid_fused(
    const float* __restrict__ x,
    const float* __restrict__ tables,
    float* __restrict__ out,
    int n)
{
    __shared__ float lds[TPB * ROWW];
    const int t = threadIdx.x;

    for (long long base = (long long)blockIdx.x * TPB; base < n;
         base += (long long)gridDim.x * TPB) {
        const int p = (int)base + t;
        float px = 0.f, py = 0.f, pz = 0.f;
        if (p < n) {
            px = x[3 * (size_t)p + 0];
            py = x[3 * (size_t)p + 1];
            pz = x[3 * (size_t)p + 2];
        }
#pragma unroll
        for (int l = 0; l < LEVELS; ++l) {
            if (p < n) {
                const unsigned idx = hash_idx(px, py, pz, c_res[l]);
                const f2v e = *reinterpret_cast<const f2v*>(
                    tables + (((size_t)l * TSIZE + idx) << 1));
                *reinterpret_cast<f2v*>(lds + t * ROWW + 2 * l) = e;
            }
            __syncthreads();
        }
#pragma unroll
        for (int it = 0; it < 8; ++it) {
            const int lp = it * 32 + (t >> 3);
            const int qq = t & 7;
            const int gp = (int)base + lp;
            if (gp < n) {
                const f2v a = *reinterpret_cast<const f2v*>(lds + lp * ROWW + 4 * qq);
                const f2v b = *reinterpret_cast<const f2v*>(lds + lp * ROWW + 4 * qq + 2);
                f4v v;
                v.x = a.x; v.y = a.y; v.z = b.x; v.w = b.y;
                __builtin_nontemporal_store(
                    v, reinterpret_cast<f4v*>(out + (size_t)gp * (2 * LEVELS) + 4 * qq));
            }
        }
        __syncthreads();
    }
}

extern "C" void kernel_launch(void* const* d_in, const int* in_sizes, int n_in,
                              void* d_out, int out_size, void* d_ws, size_t ws_size,
                              hipStream_t stream)
{
    const float* x      = (const float*)d_in[0];   // [N, 3]
    const float* tables = (const float*)d_in[1];   // [L, T, F]
    float* out          = (float*)d_out;           // [N, L*F]
    const int n = in_sizes[0] / 3;

    const int bpl = (n + CHUNK - 1) / CHUNK;       // chunks (= blocks per level)
    const size_t slab_bytes  = (size_t)bpl * LEVELS * CHUNK * sizeof(f2v);
    const size_t idx_bytes   = (size_t)bpl * LEVELS * CHUNK * sizeof(unsigned);
    const size_t dense_bytes = (size_t)(C0 + C1) * sizeof(f2v);

    if (ws_size < slab_bytes) {
        int grid = 1024;
        const int nblocks = (n + TPB - 1) / TPB;
        if (nblocks < grid) grid = nblocks;
        hashgrid_fused<<<grid, TPB, 0, stream>>>(x, tables, out, n);
        return;
    }

    f2v* ws = (f2v*)d_ws;

    if (ws_size >= slab_bytes + idx_bytes + dense_bytes) {
        // full path: remap + hash(linear lo) + LDS-dense lo + balanced hi
        unsigned* idxw = (unsigned*)((char*)d_ws + slab_bytes);
        f2v* dense = (f2v*)((char*)d_ws + slab_bytes + idx_bytes);
        const int nb = (bpl + GLO - 1) / GLO;
        const long long total_hi = 14LL * bpl;

        remap_kernel<<<(C0 + C1 + TPB - 1) / TPB, TPB, 0, stream>>>(tables, dense);
        hash_kernel<<<bpl, TPB, 0, stream>>>(x, idxw, n, 1);
        gather_lo<<<2 * nb, TPB, 0, stream>>>(idxw, dense, ws, n, bpl, nb);
        gather_kernel<<<(int)(8 * ((total_hi + 7) / 8)), TPB, 0, stream>>>(
            idxw, tables, ws, n, bpl, 2, 14);
    } else if (ws_size >= slab_bytes + idx_bytes) {
        // R7 path: all-hashed idx + 16-level balanced gather
        unsigned* idxw = (unsigned*)((char*)d_ws + slab_bytes);
        const long long total = 16LL * bpl;
        hash_kernel<<<bpl, TPB, 0, stream>>>(x, idxw, n, 0);
        gather_kernel<<<(int)(8 * ((total + 7) / 8)), TPB, 0, stream>>>(
            idxw, tables, ws, n, bpl, 0, 16);
    } else {
        // x-fed gather (333us config)
        gather_x_kernel<<<2 * 8 * bpl, TPB, 0, stream>>>(x, tables, ws, n, bpl);
    }
    assemble_kernel<<<bpl, TPB, 0, stream>>>(ws, out, n);
}

// Round 9
// 311.779 us; speedup vs baseline: 1.0603x; 1.0603x over previous
//
#include <hip/hip_runtime.h>

#define LEVELS 16
#define TSIZE 524288
#define TMASK (TSIZE - 1)
#define TPB 256
#define GPPT 8                  // gather: points per thread
#define CHUNK (TPB * GPPT)      // 2048 points per chunk/slab

typedef float f2v __attribute__((ext_vector_type(2)));
typedef float f4v __attribute__((ext_vector_type(4)));

// int(16 * 1.5**l), exact as float32
__device__ __constant__ float c_res[LEVELS] = {
    16.f, 24.f, 36.f, 54.f, 81.f, 121.f, 182.f, 273.f,
    410.f, 615.f, 922.f, 1383.f, 2075.f, 3113.f, 4670.f, 7006.f
};

__device__ __forceinline__ unsigned hash_iii(int ix, int iy, int iz)
{
    return ((unsigned)ix * 73856093u
          ^ (unsigned)iy * 19349663u
          ^ (unsigned)iz * 83492791u) & TMASK;
}

__device__ __forceinline__ unsigned hash_idx(float px, float py, float pz, float r)
{
    return hash_iii((int)floorf(px * r), (int)floorf(py * r), (int)floorf(pz * r));
}

// Evidence ledger (rounds 1-8):
//  R1 8-deep gather batching: null -> not per-wave-MLP-limited.
//  R2 spin-flag fusion: 3x regression -> never trade resident miss
//     parallelism for sync.
//  R3 NT x loads: FETCH -150MB but +20us -> feeder LATENCY is on the
//     critical resource (slot-cycles = misses x latency).
//  R4 16B/lane @ 64B-stride NT stores: WRITE 262->633MB RMW blowup ->
//     NT store insts must cover full contiguous lines per wave.
//  R5 LDS-staged x (VMEM insts 40->22, occ 82->61%): null -> not
//     request-slot- or occupancy-limited. Limiter = chip-wide MSHR
//     slot-cycles (misses x latency / ~16K outstanding lines).
//  R6 idx-precompute, NT idx stores: idx landed in HBM (900cy) -> slower.
//  R7 idx-precompute, CACHED idx stores: L3-resident feeder -> gather
//     278->210us, total 321.
//  R8 LDS-dense offload of levels 0-1: gather 210->193 (balanced 14-level
//     work list proven) but gather_lo+remap cost 23us for levels whose
//     marginal in-gather cost was 17us -> levels 0-1 were ALREADY cheap
//     (L1/L2-resident working sets). Net -9us. Offload reverted.
//  R9 (this): fold levels 0-1 into hash_kernel (coords already in regs;
//     140KB of hot table replicated per-XCD L2, level 0 fits L1). Keeps
//     R8's proven 193us 14-level gather, deletes remap/gather_lo.

// idx layout: chunk-tiled: idxw[(c*LEVELS + l)*CHUNK + local] (l>=2 used)
// ws layout: [slabs][idx]

// ---------------- Kernel 0: hash + fold levels 0-1 ---------------------------
__global__ __launch_bounds__(TPB) void hash_kernel(
    const float* __restrict__ x,
    const float* __restrict__ tables,
    unsigned* __restrict__ idxw,
    f2v* __restrict__ ws,
    int n)
{
    __shared__ float xs[CHUNK * 3];         // 24KB: this chunk's x
    const int c = blockIdx.x;
    const int t = threadIdx.x;
    const long long base = (long long)c * CHUNK;
    unsigned* __restrict__ islab = idxw + (size_t)c * LEVELS * CHUNK;
    f2v* __restrict__ slab0 = ws + (size_t)c * LEVELS * CHUNK;  // level 0
    f2v* __restrict__ slab1 = slab0 + CHUNK;                    // level 1
    const float* __restrict__ t0 = tables;
    const float* __restrict__ t1 = tables + (size_t)TSIZE * 2;

    if (base + CHUNK <= n) {
        // stage x: 6 coalesced f4v loads/thread (proven R5 pattern)
        const f4v* __restrict__ xg = reinterpret_cast<const f4v*>(x + 3 * base);
#pragma unroll
        for (int j = 0; j < 6; ++j) {
            const int s = j * TPB + t;
            *reinterpret_cast<f4v*>(&xs[4 * s]) = xg[s];
        }
        __syncthreads();

#pragma unroll
        for (int j = 0; j < GPPT; ++j) {
            const int local = j * TPB + t;
            const float px = xs[3 * local + 0];
            const float py = xs[3 * local + 1];
            const float pz = xs[3 * local + 2];

            // levels 0-1: gather here (hot 140KB tables: L1/XCD-L2 hits)
            const unsigned id0 = hash_idx(px, py, pz, 16.f);
            const unsigned id1 = hash_idx(px, py, pz, 24.f);
            const f2v e0 = *reinterpret_cast<const f2v*>(t0 + 2 * (size_t)id0);
            const f2v e1 = *reinterpret_cast<const f2v*>(t1 + 2 * (size_t)id1);

            // levels 2-15: cached idx stores (R7: L3-resident feeder)
#pragma unroll
            for (int l = 2; l < LEVELS; ++l)
                islab[l * CHUNK + local] = hash_idx(px, py, pz, c_res[l]);

            // slab stores: interleaved f2v NT (512B/wave-inst, R4 rule)
            __builtin_nontemporal_store(e0, slab0 + local);
            __builtin_nontemporal_store(e1, slab1 + local);
        }
    } else {
        // tail: guarded, cached stores
        for (int j = 0; j < GPPT; ++j) {
            const int local = j * TPB + t;
            const long long p = base + local;
            if (p < n) {
                const float px = x[3 * p + 0];
                const float py = x[3 * p + 1];
                const float pz = x[3 * p + 2];
                const unsigned id0 = hash_idx(px, py, pz, 16.f);
                const unsigned id1 = hash_idx(px, py, pz, 24.f);
                slab0[local] = *reinterpret_cast<const f2v*>(t0 + 2 * (size_t)id0);
                slab1[local] = *reinterpret_cast<const f2v*>(t1 + 2 * (size_t)id1);
                for (int l = 2; l < LEVELS; ++l)
                    islab[l * CHUNK + local] = hash_idx(px, py, pz, c_res[l]);
            }
        }
    }
}

// ---------------- Kernel A: XCD-balanced level-major gather (idx-fed) --------
// Work list w in [0, nlv*bpl), level-major. XCD k owns the contiguous range
// [floor(total*k/8), floor(total*(k+1)/8)) -> equal work per XCD; within an
// XCD the sequence is level-major, so its 4MB L2 holds ONE table at a time
// (proven R8: 193us for 14 levels). Block b: k = b&7, s = b>>3.
__global__ __launch_bounds__(TPB) void gather_kernel(
    const unsigned* __restrict__ idxr,
    const float* __restrict__ tables,
    f2v* __restrict__ ws,
    int n, int bpl, int lvl_start, int nlv)
{
    const long long total = (long long)nlv * bpl;
    const int k = blockIdx.x & 7;
    const long long s = blockIdx.x >> 3;
    const long long w = ((total * k) >> 3) + s;
    if (w >= ((total * (k + 1)) >> 3)) return;
    const int lrel = (int)(w / bpl);
    const int level = lvl_start + lrel;
    const int c = (int)(w - (long long)lrel * bpl);
    const int t = threadIdx.x;

    const float* __restrict__ tbl = tables + (size_t)level * (TSIZE * 2);
    f2v* __restrict__ slab = ws + ((size_t)c * LEVELS + level) * CHUNK;
    const unsigned* __restrict__ islab = idxr + ((size_t)c * LEVELS + level) * CHUNK;
    const long long base = (long long)c * CHUNK;

    if (base + CHUNK <= n) {
        unsigned idx[GPPT];
#pragma unroll
        for (int j = 0; j < GPPT; ++j)
            idx[j] = islab[j * TPB + t];

        // 8 independent random 8B gathers in flight (XCD-local L2)
        f2v e[GPPT];
#pragma unroll
        for (int j = 0; j < GPPT; ++j)
            e[j] = *reinterpret_cast<const f2v*>(tbl + 2 * (size_t)idx[j]);

#pragma unroll
        for (int j = 0; j < GPPT; ++j)
            __builtin_nontemporal_store(e[j], slab + j * TPB + t);
    } else {
        for (int j = 0; j < GPPT; ++j) {
            const int local = j * TPB + t;
            if (base + local < n) {
                const unsigned id = islab[local];
                const f2v e = *reinterpret_cast<const f2v*>(tbl + 2 * (size_t)id);
                __builtin_nontemporal_store(e, slab + local);
            }
        }
    }
}

// ------------- Kernel A': x-fed gather (fallback when idx doesn't fit) -------
__global__ __launch_bounds__(TPB) void gather_x_kernel(
    const float* __restrict__ x,
    const float* __restrict__ tables,
    f2v* __restrict__ ws,
    int n, int bpl)
{
    const int b = blockIdx.x;
    const int half = b / (8 * bpl);
    const int r = b % (8 * bpl);
    const int level = half * 8 + (r & 7);
    const int c = r >> 3;
    const int t = threadIdx.x;

    const float rs = c_res[level];
    const float* __restrict__ tbl = tables + (size_t)level * (TSIZE * 2);
    f2v* __restrict__ slab = ws + ((size_t)c * LEVELS + level) * CHUNK;
    const long long base = (long long)c * CHUNK;

    if (base + CHUNK <= n) {
        const float* __restrict__ xb = x + 3 * base;
        float px[GPPT], py[GPPT], pz[GPPT];
#pragma unroll
        for (int j = 0; j < GPPT; ++j) {
            const int local = j * TPB + t;
            px[j] = xb[3 * local + 0];
            py[j] = xb[3 * local + 1];
            pz[j] = xb[3 * local + 2];
        }
        unsigned idx[GPPT];
#pragma unroll
        for (int j = 0; j < GPPT; ++j)
            idx[j] = hash_idx(px[j], py[j], pz[j], rs);
        f2v e[GPPT];
#pragma unroll
        for (int j = 0; j < GPPT; ++j)
            e[j] = *reinterpret_cast<const f2v*>(tbl + 2 * (size_t)idx[j]);
#pragma unroll
        for (int j = 0; j < GPPT; ++j)
            __builtin_nontemporal_store(e[j], slab + j * TPB + t);
    } else {
#pragma unroll
        for (int j = 0; j < GPPT; ++j) {
            const int local = j * TPB + t;
            const long long p = base + local;
            if (p < n) {
                const float qx = x[3 * p + 0];
                const float qy = x[3 * p + 1];
                const float qz = x[3 * p + 2];
                const unsigned idx = hash_idx(qx, qy, qz, rs);
                const f2v e = *reinterpret_cast<const f2v*>(tbl + 2 * (size_t)idx);
                __builtin_nontemporal_store(e, slab + local);
            }
        }
    }
}

// ---------------- Kernel B: assemble (slab ws -> point-major out rows) -------
// At HBM roofline for its 524MB (~6TB/s measured). Unchanged.
__global__ __launch_bounds__(TPB) void assemble_kernel(
    const f2v* __restrict__ ws,
    float* __restrict__ out,
    int n)
{
    const int c = blockIdx.x;
    const int t = threadIdx.x;
    const int q = t & 7;
    const int sub = t >> 3;  // 0..31

    const f2v* __restrict__ wa = ws + ((size_t)c * LEVELS + 2 * q) * CHUNK;
    const f2v* __restrict__ wb = wa + CHUNK;
    const long long base = (long long)c * CHUNK;

    if (base + CHUNK <= n) {
#pragma unroll 8
        for (int u = 0; u < CHUNK / 64; ++u) {
            const int lp = 2 * (u * 32 + sub);
            const f4v a = __builtin_nontemporal_load(
                reinterpret_cast<const f4v*>(wa + lp));
            const f4v b = __builtin_nontemporal_load(
                reinterpret_cast<const f4v*>(wb + lp));
            f4v v0, v1;
            v0.x = a.x; v0.y = a.y; v0.z = b.x; v0.w = b.y;
            v1.x = a.z; v1.y = a.w; v1.z = b.z; v1.w = b.w;
            float* row = out + (size_t)(base + lp) * (2 * LEVELS) + 4 * q;
            __builtin_nontemporal_store(v0, reinterpret_cast<f4v*>(row));
            __builtin_nontemporal_store(v1, reinterpret_cast<f4v*>(row + 2 * LEVELS));
        }
    } else {
#pragma unroll 8
        for (int u = 0; u < CHUNK / 32; ++u) {
            const int lp = u * 32 + sub;
            const long long pt = base + lp;
            if (pt < n) {
                const f2v a = __builtin_nontemporal_load(wa + lp);
                const f2v b = __builtin_nontemporal_load(wb + lp);
                f4v v;
                v.x = a.x; v.y = a.y; v.z = b.x; v.w = b.y;
                __builtin_nontemporal_store(
                    v, reinterpret_cast<f4v*>(out + (size_t)pt * (2 * LEVELS) + 4 * q));
            }
        }
    }
}

// ---------------- Fallback (ws too small): round-3 fused kernel --------------
#define ROWW 34
__global__ __launch_bounds__(TPB) void hashgrid_fused(
    const float* __restrict__ x,
    const float* __restrict__ tables,
    float* __restrict__ out,
    int n)
{
    __shared__ float lds[TPB * ROWW];
    const int t = threadIdx.x;

    for (long long base = (long long)blockIdx.x * TPB; base < n;
         base += (long long)gridDim.x * TPB) {
        const int p = (int)base + t;
        float px = 0.f, py = 0.f, pz = 0.f;
        if (p < n) {
            px = x[3 * (size_t)p + 0];
            py = x[3 * (size_t)p + 1];
            pz = x[3 * (size_t)p + 2];
        }
#pragma unroll
        for (int l = 0; l < LEVELS; ++l) {
            if (p < n) {
                const unsigned idx = hash_idx(px, py, pz, c_res[l]);
                const f2v e = *reinterpret_cast<const f2v*>(
                    tables + (((size_t)l * TSIZE + idx) << 1));
                *reinterpret_cast<f2v*>(lds + t * ROWW + 2 * l) = e;
            }
            __syncthreads();
        }
#pragma unroll
        for (int it = 0; it < 8; ++it) {
            const int lp = it * 32 + (t >> 3);
            const int qq = t & 7;
            const int gp = (int)base + lp;
            if (gp < n) {
                const f2v a = *reinterpret_cast<const f2v*>(lds + lp * ROWW + 4 * qq);
                const f2v b = *reinterpret_cast<const f2v*>(lds + lp * ROWW + 4 * qq + 2);
                f4v v;
                v.x = a.x; v.y = a.y; v.z = b.x; v.w = b.y;
                __builtin_nontemporal_store(
                    v, reinterpret_cast<f4v*>(out + (size_t)gp * (2 * LEVELS) + 4 * qq));
            }
        }
        __syncthreads();
    }
}

extern "C" void kernel_launch(void* const* d_in, const int* in_sizes, int n_in,
                              void* d_out, int out_size, void* d_ws, size_t ws_size,
                              hipStream_t stream)
{
    const float* x      = (const float*)d_in[0];   // [N, 3]
    const float* tables = (const float*)d_in[1];   // [L, T, F]
    float* out          = (float*)d_out;           // [N, L*F]
    const int n = in_sizes[0] / 3;

    const int bpl = (n + CHUNK - 1) / CHUNK;       // chunks (= blocks per level)
    const size_t slab_bytes = (size_t)bpl * LEVELS * CHUNK * sizeof(f2v);
    const size_t idx_bytes  = (size_t)bpl * LEVELS * CHUNK * sizeof(unsigned);

    if (ws_size < slab_bytes) {
        int grid = 1024;
        const int nblocks = (n + TPB - 1) / TPB;
        if (nblocks < grid) grid = nblocks;
        hashgrid_fused<<<grid, TPB, 0, stream>>>(x, tables, out, n);
        return;
    }

    f2v* ws = (f2v*)d_ws;

    if (ws_size >= slab_bytes + idx_bytes) {
        // full path: hash (+levels 0-1 folded) -> balanced 14-level gather
        unsigned* idxw = (unsigned*)((char*)d_ws + slab_bytes);
        const long long total_hi = 14LL * bpl;
        hash_kernel<<<bpl, TPB, 0, stream>>>(x, tables, idxw, ws, n);
        gather_kernel<<<(int)(8 * ((total_hi + 7) / 8)), TPB, 0, stream>>>(
            idxw, tables, ws, n, bpl, 2, 14);
    } else {
        // x-fed gather (333us config)
        gather_x_kernel<<<2 * 8 * bpl, TPB, 0, stream>>>(x, tables, ws, n, bpl);
    }
    assemble_kernel<<<bpl, TPB, 0, stream>>>(ws, out, n);
}